// Round 4
// baseline (393.147 us; speedup 1.0000x reference)
//
#include <hip/hip_runtime.h>
#include <hip/hip_bf16.h>

typedef __attribute__((ext_vector_type(8))) short short8;
typedef __attribute__((ext_vector_type(4))) float floatx4;

#define MFMA16(a, b, c) __builtin_amdgcn_mfma_f32_16x16x32_bf16((a), (b), (c), 0, 0, 0)
#define GLOBAL_AS __attribute__((address_space(1)))
#define LDS_AS __attribute__((address_space(3)))

__device__ __forceinline__ unsigned short f2bf(float x) {
  union { float f; unsigned u; } v; v.f = x;
  unsigned r = v.u + 0x7FFFu + ((v.u >> 16) & 1u);  // RNE
  return (unsigned short)(r >> 16);
}

__device__ __forceinline__ short8 ld8(const unsigned short* p) {
  return *reinterpret_cast<const short8*>(p);
}

// async global->LDS, 16B per lane; LDS dest = wave-uniform base + lane*16
__device__ __forceinline__ void async_cp16(const unsigned short* g, unsigned short* l) {
  __builtin_amdgcn_global_load_lds((const GLOBAL_AS void*)g, (LDS_AS void*)l, 16, 0, 0);
}

// ---------------- fp32 -> bf16 convert (vectorized) ----------------
__global__ void k_f32_to_bf16(const float* __restrict__ in,
                              unsigned short* __restrict__ out, int n4) {
  int i = blockIdx.x * blockDim.x + threadIdx.x;
  if (i >= n4) return;
  float4 f = reinterpret_cast<const float4*>(in)[i];
  union { unsigned short u[4]; unsigned long long v; } o;
  o.u[0] = f2bf(f.x); o.u[1] = f2bf(f.y); o.u[2] = f2bf(f.z); o.u[3] = f2bf(f.w);
  reinterpret_cast<unsigned long long*>(out)[i] = o.v;
}

// ---------------- transpose + convert: out[c][r] = bf16(in[r][c]) ----------------
__global__ void k_transpose_bf16(const float* __restrict__ in,
                                 unsigned short* __restrict__ out, int R, int C) {
  __shared__ float tile[64][65];
  int c0 = blockIdx.x * 64, r0 = blockIdx.y * 64;
  int tx = threadIdx.x, ty = threadIdx.y;
  for (int i = ty; i < 64; i += 4)
    tile[i][tx] = in[(size_t)(r0 + i) * C + c0 + tx];
  __syncthreads();
  for (int i = ty; i < 64; i += 4)
    out[(size_t)(c0 + i) * R + r0 + tx] = f2bf(tile[tx][i]);
}

// ---------------- V transpose (bf16): vT[bh][d][t] = qkv[b*T+t][2048+h*64+d] ----
__global__ void k_vtrans(const unsigned short* __restrict__ qkvb,
                         unsigned short* __restrict__ vT) {
  const int T = 2048, LD = 3072;
  __shared__ unsigned short tile[64][72];
  int bh = blockIdx.y, b = bh >> 4, h = bh & 15;
  int t0 = blockIdx.x * 64;
  int tx = threadIdx.x, ty = threadIdx.y;
  const unsigned short* src = qkvb + (size_t)b * T * LD + 2048 + h * 64;
  for (int i = ty; i < 64; i += 4)
    tile[i][tx] = src[(size_t)(t0 + i) * LD + tx];
  __syncthreads();
  unsigned short* dst = vT + (size_t)bh * 64 * T;
  for (int i = ty; i < 64; i += 4)
    dst[(size_t)i * T + t0 + tx] = tile[tx][i];
}

// ---------------- GEMM: C[M,N] = A[M,K] @ Bt[N,K]^T, BK=64, global_load_lds ----
// 128x128 tile / 256-thread block, 4 waves 2x2, each wave 64x64 (4x4 frags).
// LDS UNPADDED (row stride 64 bf16 = 128B): required by global_load_lds
// lane-contiguous placement (wave-uniform base + lane*16).
template <int OUT_BF16, int HAS_BIAS>
__global__ __launch_bounds__(256) void k_gemm_bt(
    const unsigned short* __restrict__ A, const unsigned short* __restrict__ Bt,
    void* __restrict__ Cout, const float* __restrict__ bias, int M, int N, int K) {
  __shared__ unsigned short As[128][64];
  __shared__ unsigned short Bs[128][64];
  int tid = threadIdx.x;
  int w = tid >> 6, lane = tid & 63, quad = lane >> 4, l16 = lane & 15;
  int wy = w >> 1, wx = w & 1;
  int rowB = blockIdx.y * 128, colB = blockIdx.x * 128;
  int srcRow = lane >> 3, srcCol = (lane & 7) << 3;  // 8 rows x 128B per wave-instr

  floatx4 acc[4][4];
  floatx4 zero4 = {0.f, 0.f, 0.f, 0.f};
#pragma unroll
  for (int mi = 0; mi < 4; ++mi)
#pragma unroll
    for (int ni = 0; ni < 4; ++ni) acc[mi][ni] = zero4;

  for (int kt = 0; kt < K; kt += 64) {
    __syncthreads();
    // each wave issues 4 As + 4 Bs async copies of 8 rows (1KB) each
#pragma unroll
    for (int i = 0; i < 4; ++i) {
      int r0 = w * 32 + i * 8;
      async_cp16(&A[(size_t)(rowB + r0 + srcRow) * K + kt + srcCol], &As[r0][0]);
      async_cp16(&Bt[(size_t)(colB + r0 + srcRow) * K + kt + srcCol], &Bs[r0][0]);
    }
    __syncthreads();  // drains vmcnt (global_load_lds) before LDS reads
#pragma unroll
    for (int kh = 0; kh < 2; ++kh) {
      short8 af[4], bf_[4];
#pragma unroll
      for (int mi = 0; mi < 4; ++mi)
        af[mi] = ld8(&As[wy * 64 + mi * 16 + l16][kh * 32 + quad * 8]);
#pragma unroll
      for (int ni = 0; ni < 4; ++ni)
        bf_[ni] = ld8(&Bs[wx * 64 + ni * 16 + l16][kh * 32 + quad * 8]);
#pragma unroll
      for (int mi = 0; mi < 4; ++mi)
#pragma unroll
        for (int ni = 0; ni < 4; ++ni)
          acc[mi][ni] = MFMA16(af[mi], bf_[ni], acc[mi][ni]);
    }
  }

  // epilogue: C/D layout col=lane&15, row=quad*4+reg
#pragma unroll
  for (int mi = 0; mi < 4; ++mi) {
    int row = rowB + wy * 64 + mi * 16 + quad * 4;
#pragma unroll
    for (int ni = 0; ni < 4; ++ni) {
      int col = colB + wx * 64 + ni * 16 + l16;
      float bv = HAS_BIAS ? bias[col] : 0.f;
#pragma unroll
      for (int r = 0; r < 4; ++r) {
        float val = acc[mi][ni][r] + bv;
        if (OUT_BF16)
          ((unsigned short*)Cout)[(size_t)(row + r) * N + col] = f2bf(val);
        else
          ((float*)Cout)[(size_t)(row + r) * N + col] = val;
      }
    }
  }
}

// ---------------- flash attention, causal, BARRIER-FREE ----------------
// Each wave independently owns 16 q-rows, streams K/V^T fragments straight
// from global (L2-resident: 512KB per bh), online softmax in registers,
// P repack through wave-private LDS (no __syncthreads anywhere).
// qkv: [B*T][3072] bf16; vT: [B*H][64][T] bf16; out: [B*T][1024] bf16.
// grid (T/64, B*H) with x reversed so long strips launch first; block 256.
__global__ __launch_bounds__(256) void k_attn(
    const unsigned short* __restrict__ qkv, const unsigned short* __restrict__ vT,
    unsigned short* __restrict__ attn_out) {
  const int T = 2048, LD = 3072;
  __shared__ unsigned short Pt[4][16][68];  // per-wave P buffer; writes conflict-free

  int bh = blockIdx.y, b = bh >> 4, h = bh & 15;
  int qblk = gridDim.x - 1 - blockIdx.x;  // reversed: most-work blocks first
  int tid = threadIdx.x, w = tid >> 6, lane = tid & 63;
  int quad = lane >> 4, l16 = lane & 15;
  int q0w = qblk * 64 + w * 16;  // this wave's 16 q-rows

  const unsigned short* Qp = qkv + (size_t)b * T * LD + h * 64;
  const unsigned short* Kp = Qp + 1024;
  const unsigned short* Vp = vT + (size_t)bh * 64 * T;

  // Q fragments (A-layout: m=l16, k=quad*8+j)
  short8 aq[2];
  {
    const unsigned short* qrow = Qp + (size_t)(q0w + l16) * LD + quad * 8;
    aq[0] = ld8(qrow);
    aq[1] = ld8(qrow + 32);
  }

  // softmax state in exp2 domain: fold scale*log2(e) into scores
  const float cscale = 0.125f * 1.44269504f;
  float m_i[4], l_i[4];
  floatx4 o_acc[4];
  floatx4 zero4 = {0.f, 0.f, 0.f, 0.f};
#pragma unroll
  for (int r = 0; r < 4; ++r) { m_i[r] = -1e30f; l_i[r] = 0.f; }
#pragma unroll
  for (int nd = 0; nd < 4; ++nd) o_acc[nd] = zero4;

  int nt = (q0w >> 6) + 1;  // key tiles of 64 covering keys <= q0w+15
  int qrow_rel = quad * 4;  // + r = row within the wave's 16
  for (int kt = 0; kt < nt; ++kt) {
    int key0 = kt * 64;

    // S = Q K^T : K B-frags straight from global (n=key row, k=d)
    floatx4 s[4];
#pragma unroll
    for (int nk = 0; nk < 4; ++nk) {
      const unsigned short* krow = Kp + (size_t)(key0 + nk * 16 + l16) * LD + quad * 8;
      short8 bk0 = ld8(krow);
      short8 bk1 = ld8(krow + 32);
      s[nk] = MFMA16(aq[0], bk0, zero4);
      s[nk] = MFMA16(aq[1], bk1, s[nk]);
    }

    bool diag = (kt == nt - 1);
#pragma unroll
    for (int nk = 0; nk < 4; ++nk)
#pragma unroll
      for (int r = 0; r < 4; ++r) {
        float sv = s[nk][r] * cscale;
        if (diag && (key0 + nk * 16 + l16 > q0w + qrow_rel + r)) sv = -1e30f;
        s[nk][r] = sv;
      }

    // online softmax (exp2 domain); each row's 64 keys: 16 lanes x 4 frags
    float alpha[4];
#pragma unroll
    for (int r = 0; r < 4; ++r) {
      float tm = fmaxf(fmaxf(s[0][r], s[1][r]), fmaxf(s[2][r], s[3][r]));
      tm = fmaxf(tm, __shfl_xor(tm, 1));
      tm = fmaxf(tm, __shfl_xor(tm, 2));
      tm = fmaxf(tm, __shfl_xor(tm, 4));
      tm = fmaxf(tm, __shfl_xor(tm, 8));
      float mn = fmaxf(m_i[r], tm);
      alpha[r] = exp2f(m_i[r] - mn);
      m_i[r] = mn;
      float rs = 0.f;
#pragma unroll
      for (int nk = 0; nk < 4; ++nk) {
        float p = exp2f(s[nk][r] - mn);
        s[nk][r] = p;
        rs += p;
      }
      rs += __shfl_xor(rs, 1);
      rs += __shfl_xor(rs, 2);
      rs += __shfl_xor(rs, 4);
      rs += __shfl_xor(rs, 8);
      l_i[r] = l_i[r] * alpha[r] + rs;
    }

    // P -> wave-private LDS (in-order per wave; no barrier needed)
#pragma unroll
    for (int nk = 0; nk < 4; ++nk)
#pragma unroll
      for (int r = 0; r < 4; ++r)
        Pt[w][quad * 4 + r][nk * 16 + l16] = f2bf(s[nk][r]);
#pragma unroll
    for (int nd = 0; nd < 4; ++nd)
#pragma unroll
      for (int r = 0; r < 4; ++r) o_acc[nd][r] *= alpha[r];

    // O += P V : P A-frags from LDS, V^T B-frags straight from global (n=d, k=key)
    short8 pa0 = ld8(&Pt[w][l16][quad * 8]);
    short8 pa1 = ld8(&Pt[w][l16][32 + quad * 8]);
#pragma unroll
    for (int nd = 0; nd < 4; ++nd) {
      const unsigned short* vrow = Vp + (size_t)(nd * 16 + l16) * T + key0 + quad * 8;
      short8 bv0 = ld8(vrow);
      short8 bv1 = ld8(vrow + 32);
      o_acc[nd] = MFMA16(pa0, bv0, o_acc[nd]);
      o_acc[nd] = MFMA16(pa1, bv1, o_acc[nd]);
    }
  }

  // epilogue: attn_out [B*T][1024] bf16
#pragma unroll
  for (int nd = 0; nd < 4; ++nd)
#pragma unroll
    for (int r = 0; r < 4; ++r) {
      int q = q0w + quad * 4 + r;
      int d = nd * 16 + l16;
      attn_out[(size_t)(b * T + q) * 1024 + h * 64 + d] =
          f2bf(o_acc[nd][r] / l_i[r]);
    }
}

extern "C" void kernel_launch(void* const* d_in, const int* in_sizes, int n_in,
                              void* d_out, int out_size, void* d_ws, size_t ws_size,
                              hipStream_t stream) {
  const float* x = (const float*)d_in[0];       // [2,2048,1024]
  const float* w_qkv = (const float*)d_in[1];   // [1024,3072]
  const float* w_proj = (const float*)d_in[2];  // [1024,1024]
  const float* b_proj = (const float*)d_in[3];  // [1024]
  float* out = (float*)d_out;                   // [2,2048,1024] fp32

  char* ws = (char*)d_ws;
  unsigned short* xb     = (unsigned short*)(ws);                      // 8 MB (dead after QKV GEMM)
  unsigned short* wqkvT  = (unsigned short*)(ws + (size_t)(8  << 20)); // 6 MB
  unsigned short* wprojT = (unsigned short*)(ws + (size_t)(14 << 20)); // 2 MB
  unsigned short* qkvb   = (unsigned short*)(ws + (size_t)(16 << 20)); // 24 MB
  unsigned short* attnb  = (unsigned short*)(ws + (size_t)(40 << 20)); // 8 MB
  unsigned short* vTb    = xb;                                         // reuse xb region

  k_f32_to_bf16<<<4096, 256, 0, stream>>>(x, xb, (4096 * 1024) / 4);
  dim3 tb(64, 4);
  k_transpose_bf16<<<dim3(3072 / 64, 1024 / 64), tb, 0, stream>>>(w_qkv, wqkvT, 1024, 3072);
  k_transpose_bf16<<<dim3(1024 / 64, 1024 / 64), tb, 0, stream>>>(w_proj, wprojT, 1024, 1024);
  k_gemm_bt<1, 0><<<dim3(3072 / 128, 4096 / 128), 256, 0, stream>>>(
      xb, wqkvT, qkvb, nullptr, 4096, 3072, 1024);
  k_vtrans<<<dim3(2048 / 64, 2 * 16), tb, 0, stream>>>(qkvb, vTb);
  k_attn<<<dim3(2048 / 64, 2 * 16), 256, 0, stream>>>(qkvb, vTb, attnb);
  k_gemm_bt<0, 1><<<dim3(1024 / 128, 4096 / 128), 256, 0, stream>>>(
      attnb, wprojT, out, b_proj, 4096, 1024, 1024);
}